// Round 8
// baseline (381.153 us; speedup 1.0000x reference)
//
#include <hip/hip_runtime.h>

#define NN 2048
#define HALF 1024
#define CC 128
#define EE 65536
#define CAP 128
#define TCT 16   /* contributors per tile: 8 dense chunks + 8 sparse pairs */

typedef unsigned short u16;

__device__ __forceinline__ float sigm(float v){ return 1.0f/(1.0f + __expf(-v)); }

// ---------------- K1: prep (384 blocks)
//  all blocks: strided zero of AGG1+AGG2 (131072 float4) + 128 tile counters
//  blocks [0,128):   SpRaw[r][c]=sigm(my[r][c]) + colsum atomics
//  blocks [128,384): bucket sparse edges by dst
//  last block: dinv
__global__ __launch_bounds__(256) void k_prep(
    const float* __restrict__ my, const int* __restrict__ ei,
    float* __restrict__ SpRaw, float* __restrict__ colsum,
    int* __restrict__ cnt, u16* __restrict__ bucket,
    int* __restrict__ done, float* __restrict__ dinv,
    float* __restrict__ AGGz, int* __restrict__ tcz)
{
  int b = blockIdx.x, t = threadIdx.x;
  int gid = b*256 + t;
  if (gid < 65536) ((float4*)AGGz)[gid] = make_float4(0.f,0.f,0.f,0.f);
  if (gid < 128) tcz[gid] = 0;

  if (b < 128) {
    int c0 = t*4;
    float cs0=0.f, cs1=0.f, cs2=0.f, cs3=0.f;
    #pragma unroll 2
    for (int rr=0; rr<8; ++rr){
      int r = b*8 + rr;
      float4 v = *(const float4*)(my + (size_t)r*NN + c0);
      float s0=sigm(v.x), s1=sigm(v.y), s2=sigm(v.z), s3=sigm(v.w);
      *(float4*)(SpRaw + (size_t)r*HALF + c0) = make_float4(s0,s1,s2,s3);
      cs0+=s0; cs1+=s1; cs2+=s2; cs3+=s3;
    }
    atomicAdd(&colsum[c0+0], cs0);
    atomicAdd(&colsum[c0+1], cs1);
    atomicAdd(&colsum[c0+2], cs2);
    atomicAdd(&colsum[c0+3], cs3);
  } else {
    int e = (b-128)*256 + t;
    int s = ei[e], d = ei[EE + e];
    int slot = atomicAdd(&cnt[d], 1);
    if (slot < CAP) bucket[d*CAP + slot] = (u16)s;
  }

  __shared__ int lastf;
  __threadfence();
  __syncthreads();
  if (t == 0) {
    int v = __hip_atomic_fetch_add(done, 1, __ATOMIC_ACQ_REL, __HIP_MEMORY_SCOPE_AGENT);
    lastf = (v == 383) ? 1 : 0;
  }
  __syncthreads();
  if (lastf) {
    for (int i = t; i < NN; i += 256) {
      int c = __hip_atomic_load(&cnt[i], __ATOMIC_RELAXED, __HIP_MEMORY_SCOPE_AGENT);
      float cs = 0.f;
      if (i < HALF)
        cs = __hip_atomic_load(&colsum[i], __ATOMIC_RELAXED, __HIP_MEMORY_SCOPE_AGENT);
      dinv[i] = rsqrtf(1.0f + (float)c + cs);
    }
  }
}

// returns 1 for the last contributor of this tile
__device__ __forceinline__ int finish_tile(int* __restrict__ tcnt, int tile, int t, int* lastf){
  __threadfence();
  __syncthreads();
  if (t == 0) {
    int v = __hip_atomic_fetch_add(&tcnt[tile], 1, __ATOMIC_ACQ_REL, __HIP_MEMORY_SCOPE_AGENT);
    *lastf = (v == TCT-1) ? 1 : 0;
  }
  __syncthreads();
  return *lastf;
}

// ---------------- layer A: agg of x -> (fused) hidden = relu(. @ W1 + b1)
//  blocks [0,512):     dense chunk (tile=b>>3, chunk=b&7)
//  blocks [512,1024):  sparse pair for rows<1024 (tile=(b-512)>>3, pair=(b-512)&7)
//  blocks [1024,1536): rows>=1024 self-contained
__global__ __launch_bounds__(256) void k_layerA(
  const float* __restrict__ SpRaw, const float* __restrict__ x, const float* __restrict__ dinv,
  const int* __restrict__ cnt, const u16* __restrict__ bucket,
  float* __restrict__ AGG, int* __restrict__ tcnt,
  const float* __restrict__ W1, const float* __restrict__ b1, float* __restrict__ hid)
{
  __shared__ float la[16][CC];
  __shared__ int lastf;
  int b = blockIdx.x, t = threadIdx.x;
  int f = t & 127, h = t >> 7;
  int tile = -1;

  if (b < 512) {
    tile = b >> 3;
    int db = tile*16 + h*8;
    int r0 = (b & 7)*128;
    float acc[8];
    #pragma unroll
    for (int j=0;j<8;j++) acc[j] = 0.f;
    #pragma unroll 4
    for (int r=r0; r<r0+128; ++r){
      float fv = x[(size_t)r*CC + f] * dinv[r];
      const float4* sp4 = (const float4*)(SpRaw + (size_t)r*HALF + db);
      float4 s0 = sp4[0], s1 = sp4[1];
      acc[0] = fmaf(s0.x, fv, acc[0]);
      acc[1] = fmaf(s0.y, fv, acc[1]);
      acc[2] = fmaf(s0.z, fv, acc[2]);
      acc[3] = fmaf(s0.w, fv, acc[3]);
      acc[4] = fmaf(s1.x, fv, acc[4]);
      acc[5] = fmaf(s1.y, fv, acc[5]);
      acc[6] = fmaf(s1.z, fv, acc[6]);
      acc[7] = fmaf(s1.w, fv, acc[7]);
    }
    #pragma unroll
    for (int j=0;j<8;j++)
      atomicAdd(&AGG[(size_t)(db+j)*CC + f], acc[j]*dinv[db+j]);
  } else if (b < 1024) {
    int idx = b - 512;
    tile = idx >> 3;
    int d = tile*16 + (idx & 7)*2 + h;
    float dd = dinv[d];
    float a = dd * x[(size_t)d*CC + f];
    int m = cnt[d]; m = m > CAP ? CAP : m;
    const u16* bk = bucket + d*CAP;
    for (int j=0;j<m;j++){
      int s = bk[j];
      a = fmaf(dinv[s], x[(size_t)s*CC + f], a);
    }
    atomicAdd(&AGG[(size_t)d*CC + f], a*dd);
  } else {
    int d = HALF + (b-1024)*2 + h;
    float dd = dinv[d];
    float a = dd * x[(size_t)d*CC + f];
    int m = cnt[d]; m = m > CAP ? CAP : m;
    const u16* bk = bucket + d*CAP;
    for (int j=0;j<m;j++){
      int s = bk[j];
      a = fmaf(dinv[s], x[(size_t)s*CC + f], a);
    }
    la[h][f] = a * dd;
    __syncthreads();
    float o = b1[f];
    #pragma unroll 4
    for (int k=0;k<CC;k++)
      o = fmaf(la[h][k], W1[k*CC + f], o);
    hid[(size_t)d*CC + f] = o > 0.f ? o : 0.f;
    return;
  }

  if (finish_tile(tcnt, tile, t, &lastf)) {
    int row0 = tile*16;
    #pragma unroll
    for (int i=0;i<8;i++){
      int idx = i*256 + t;
      int r = idx >> 7, c = idx & 127;
      la[r][c] = __hip_atomic_load(&AGG[(size_t)(row0+r)*CC + c],
                                   __ATOMIC_RELAXED, __HIP_MEMORY_SCOPE_AGENT);
    }
    __syncthreads();
    float o[8];
    float bb = b1[f];
    #pragma unroll
    for (int i=0;i<8;i++) o[i] = bb;
    #pragma unroll 4
    for (int k=0;k<CC;k++){
      float w = W1[k*CC + f];
      #pragma unroll
      for (int i=0;i<8;i++) o[i] = fmaf(la[h*8+i][k], w, o[i]);
    }
    #pragma unroll
    for (int i=0;i<8;i++){
      float v = o[i];
      hid[(size_t)(row0 + h*8 + i)*CC + f] = v > 0.f ? v : 0.f;
    }
  }
}

// ---------------- layer B: agg of hid -> (fused) z = . @ [Wmu|Wls] + [bmu|bls] -> out
__global__ __launch_bounds__(256) void k_layerB(
  const float* __restrict__ SpRaw, const float* __restrict__ hid, const float* __restrict__ dinv,
  const int* __restrict__ cnt, const u16* __restrict__ bucket,
  float* __restrict__ AGG, int* __restrict__ tcnt,
  const float* __restrict__ Wmu, const float* __restrict__ bmu,
  const float* __restrict__ Wls, const float* __restrict__ bls,
  float* __restrict__ out)
{
  __shared__ float la[16][CC];
  __shared__ int lastf;
  int b = blockIdx.x, t = threadIdx.x;
  int f = t & 127, h = t >> 7;
  const float* W = (f < 64) ? Wmu : Wls;
  int g = f & 63;
  size_t obase = (f < 64) ? 0 : (size_t)NN*64;
  int tile = -1;

  if (b < 512) {
    tile = b >> 3;
    int db = tile*16 + h*8;
    int r0 = (b & 7)*128;
    float acc[8];
    #pragma unroll
    for (int j=0;j<8;j++) acc[j] = 0.f;
    #pragma unroll 4
    for (int r=r0; r<r0+128; ++r){
      float fv = hid[(size_t)r*CC + f] * dinv[r];
      const float4* sp4 = (const float4*)(SpRaw + (size_t)r*HALF + db);
      float4 s0 = sp4[0], s1 = sp4[1];
      acc[0] = fmaf(s0.x, fv, acc[0]);
      acc[1] = fmaf(s0.y, fv, acc[1]);
      acc[2] = fmaf(s0.z, fv, acc[2]);
      acc[3] = fmaf(s0.w, fv, acc[3]);
      acc[4] = fmaf(s1.x, fv, acc[4]);
      acc[5] = fmaf(s1.y, fv, acc[5]);
      acc[6] = fmaf(s1.z, fv, acc[6]);
      acc[7] = fmaf(s1.w, fv, acc[7]);
    }
    #pragma unroll
    for (int j=0;j<8;j++)
      atomicAdd(&AGG[(size_t)(db+j)*CC + f], acc[j]*dinv[db+j]);
  } else if (b < 1024) {
    int idx = b - 512;
    tile = idx >> 3;
    int d = tile*16 + (idx & 7)*2 + h;
    float dd = dinv[d];
    float a = dd * hid[(size_t)d*CC + f];
    int m = cnt[d]; m = m > CAP ? CAP : m;
    const u16* bk = bucket + d*CAP;
    for (int j=0;j<m;j++){
      int s = bk[j];
      a = fmaf(dinv[s], hid[(size_t)s*CC + f], a);
    }
    atomicAdd(&AGG[(size_t)d*CC + f], a*dd);
  } else {
    int d = HALF + (b-1024)*2 + h;
    float dd = dinv[d];
    float a = dd * hid[(size_t)d*CC + f];
    int m = cnt[d]; m = m > CAP ? CAP : m;
    const u16* bk = bucket + d*CAP;
    for (int j=0;j<m;j++){
      int s = bk[j];
      a = fmaf(dinv[s], hid[(size_t)s*CC + f], a);
    }
    la[h][f] = a * dd;
    __syncthreads();
    float o = (f < 64) ? bmu[g] : bls[g];
    #pragma unroll 4
    for (int k=0;k<CC;k++)
      o = fmaf(la[h][k], W[k*64 + g], o);
    out[obase + (size_t)d*64 + g] = o;
    return;
  }

  if (finish_tile(tcnt, tile, t, &lastf)) {
    int row0 = tile*16;
    #pragma unroll
    for (int i=0;i<8;i++){
      int idx = i*256 + t;
      int r = idx >> 7, c = idx & 127;
      la[r][c] = __hip_atomic_load(&AGG[(size_t)(row0+r)*CC + c],
                                   __ATOMIC_RELAXED, __HIP_MEMORY_SCOPE_AGENT);
    }
    __syncthreads();
    float o[8];
    float bb = (f < 64) ? bmu[g] : bls[g];
    #pragma unroll
    for (int i=0;i<8;i++) o[i] = bb;
    #pragma unroll 4
    for (int k=0;k<CC;k++){
      float w = W[k*64 + g];
      #pragma unroll
      for (int i=0;i<8;i++) o[i] = fmaf(la[h*8+i][k], w, o[i]);
    }
    #pragma unroll
    for (int i=0;i<8;i++)
      out[obase + (size_t)(row0 + h*8 + i)*64 + g] = o[i];
  }
}

extern "C" void kernel_launch(void* const* d_in, const int* in_sizes, int n_in,
                              void* d_out, int out_size, void* d_ws, size_t ws_size,
                              hipStream_t stream)
{
  (void)in_sizes; (void)n_in; (void)out_size; (void)ws_size;
  const float* x   = (const float*)d_in[0];
  const float* my  = (const float*)d_in[1];
  const float* W1  = (const float*)d_in[2];
  const float* b1  = (const float*)d_in[3];
  const float* Wmu = (const float*)d_in[4];
  const float* bmu = (const float*)d_in[5];
  const float* Wls = (const float*)d_in[6];
  const float* bls = (const float*)d_in[7];
  const int*   ei  = (const int*)d_in[8];
  float* out = (float*)d_out;
  char* ws = (char*)d_ws;

  // ws layout — memset only covers cnt+colsum+done (12352 B); prep zeroes AGG1/AGG2/tc.
  int*   cnt    = (int*)  (ws + 0);        //    8192 B (memset 0)
  float* colsum = (float*)(ws + 8192);     //    4096 B (memset 0)
  int*   done   = (int*)  (ws + 12288);    //      64 B (memset 0)
  int*   tc1    = (int*)  (ws + 12352);    //     256 B (prep zeroes; tc2 contiguous)
  int*   tc2    = (int*)  (ws + 12608);    //     256 B
  float* dinv   = (float*)(ws + 12864);    //    8192 B
  u16*   bucket = (u16*)  (ws + 21056);    //  524288 B
  float* SpRaw  = (float*)(ws + 545344);   // 4194304 B
  float* AGG1   = (float*)(ws + 4739648);  //  524288 B (rows<1024 only; AGG2 contiguous)
  float* AGG2   = (float*)(ws + 5263936);  //  524288 B
  float* hid    = (float*)(ws + 5788224);  // 1048576 B

  hipMemsetAsync(ws, 0, 12352, stream);
  k_prep  <<<384,  256, 0, stream>>>(my, ei, SpRaw, colsum, cnt, bucket, done, dinv, AGG1, tc1);
  k_layerA<<<1536, 256, 0, stream>>>(SpRaw, x,   dinv, cnt, bucket, AGG1, tc1, W1, b1, hid);
  k_layerB<<<1536, 256, 0, stream>>>(SpRaw, hid, dinv, cnt, bucket, AGG2, tc2, Wmu, bmu, Wls, bls, out);
}

// Round 9
// 188.262 us; speedup vs baseline: 2.0246x; 2.0246x over previous
//
#include <hip/hip_runtime.h>

#define NN 2048
#define HALF 1024
#define CC 128
#define EE 65536
#define CAP 128

typedef unsigned short u16;

__device__ __forceinline__ float sigm(float v){ return 1.0f/(1.0f + __expf(-v)); }

// ---------------- K1: prep (640 blocks)
//  [0,128):   SpRaw[r][c]=sigm(my[r][c]) (coalesced) + colsum atomics
//  [128,384): bucket sparse edges by dst
//  [384,640): H0 = x @ W1  (8 rows/block, LDS-staged)
//  last-finishing block: dinv = rsqrt(1 + cnt + colsum)   (fence-free done-counter, r7-proven)
__global__ __launch_bounds__(256) void k_prep(
    const float* __restrict__ my, const int* __restrict__ ei, const float* __restrict__ x,
    const float* __restrict__ W1,
    float* __restrict__ SpRaw, float* __restrict__ colsum,
    int* __restrict__ cnt, u16* __restrict__ bucket,
    int* __restrict__ done, float* __restrict__ dinv, float* __restrict__ H0)
{
  __shared__ float la[8][CC];
  int b = blockIdx.x, t = threadIdx.x;
  if (b < 128) {
    int c0 = t*4;
    float cs0=0.f, cs1=0.f, cs2=0.f, cs3=0.f;
    #pragma unroll 2
    for (int rr=0; rr<8; ++rr){
      int r = b*8 + rr;
      float4 v = *(const float4*)(my + (size_t)r*NN + c0);
      float s0=sigm(v.x), s1=sigm(v.y), s2=sigm(v.z), s3=sigm(v.w);
      *(float4*)(SpRaw + (size_t)r*HALF + c0) = make_float4(s0,s1,s2,s3);
      cs0+=s0; cs1+=s1; cs2+=s2; cs3+=s3;
    }
    atomicAdd(&colsum[c0+0], cs0);
    atomicAdd(&colsum[c0+1], cs1);
    atomicAdd(&colsum[c0+2], cs2);
    atomicAdd(&colsum[c0+3], cs3);
  } else if (b < 384) {
    int e = (b-128)*256 + t;
    int s = ei[e], d = ei[EE + e];
    int slot = atomicAdd(&cnt[d], 1);
    if (slot < CAP) bucket[d*CAP + slot] = (u16)s;
  } else {
    int row0 = (b-384)*8;
    #pragma unroll
    for (int i=0;i<4;i++){
      int idx = i*256 + t;
      la[idx>>7][idx&127] = x[(size_t)row0*CC + idx];
    }
    __syncthreads();
    int f = t & 127, rh = t >> 7;
    float o[4] = {0.f,0.f,0.f,0.f};
    #pragma unroll 4
    for (int k=0;k<CC;k++){
      float w = W1[k*CC + f];
      o[0] = fmaf(la[rh*4+0][k], w, o[0]);
      o[1] = fmaf(la[rh*4+1][k], w, o[1]);
      o[2] = fmaf(la[rh*4+2][k], w, o[2]);
      o[3] = fmaf(la[rh*4+3][k], w, o[3]);
    }
    #pragma unroll
    for (int i=0;i<4;i++)
      H0[(size_t)(row0 + rh*4 + i)*CC + f] = o[i];
  }

  // ---- last-block computes dinv (no explicit threadfence; r7-validated) ----
  __shared__ int lastf;
  __syncthreads();
  if (t == 0) {
    int v = __hip_atomic_fetch_add(done, 1, __ATOMIC_ACQ_REL, __HIP_MEMORY_SCOPE_AGENT);
    lastf = (v == 639) ? 1 : 0;
  }
  __syncthreads();
  if (lastf) {
    for (int i = t; i < NN; i += 256) {
      int c = __hip_atomic_load(&cnt[i], __ATOMIC_RELAXED, __HIP_MEMORY_SCOPE_AGENT);
      float cs = 0.f;
      if (i < HALF)
        cs = __hip_atomic_load(&colsum[i], __ATOMIC_RELAXED, __HIP_MEMORY_SCOPE_AGENT);
      dinv[i] = rsqrtf(1.0f + (float)c + cs);
    }
  }
}

// ---------------- K2: AGG1 = Â H0  (round-5 structure: dense K-split + sparse, fp32 atomics)
__global__ __launch_bounds__(256) void k_layer1(
  const float* __restrict__ SpRaw, const float* __restrict__ F, const float* __restrict__ dinv,
  const int* __restrict__ cnt, const u16* __restrict__ bucket, float* __restrict__ AGG)
{
  int b = blockIdx.x, t = threadIdx.x;
  if (b < 256) {
    int f = t & 127, half = t >> 7;
    int dbase = (b>>2)*16 + half*8;
    int r0 = (b&3)*256;
    float acc[8];
    #pragma unroll
    for (int j=0;j<8;j++) acc[j] = 0.f;
    #pragma unroll 4
    for (int r=r0; r<r0+256; ++r){
      float fv = F[(size_t)r*CC + f] * dinv[r];
      const float4* sp4 = (const float4*)(SpRaw + (size_t)r*HALF + dbase);
      float4 s0 = sp4[0], s1 = sp4[1];
      acc[0] = fmaf(s0.x, fv, acc[0]);
      acc[1] = fmaf(s0.y, fv, acc[1]);
      acc[2] = fmaf(s0.z, fv, acc[2]);
      acc[3] = fmaf(s0.w, fv, acc[3]);
      acc[4] = fmaf(s1.x, fv, acc[4]);
      acc[5] = fmaf(s1.y, fv, acc[5]);
      acc[6] = fmaf(s1.z, fv, acc[6]);
      acc[7] = fmaf(s1.w, fv, acc[7]);
    }
    #pragma unroll
    for (int j=0;j<8;j++)
      atomicAdd(&AGG[(size_t)(dbase+j)*CC + f], acc[j]*dinv[dbase+j]);
  } else {
    int idx = b - 256;
    int d = idx*2 + (t>>7), f = t & 127;
    float dd = dinv[d];
    float acc = dd * F[(size_t)d*CC + f];
    int m = cnt[d]; m = m > CAP ? CAP : m;
    const u16* bk = bucket + d*CAP;
    for (int j=0;j<m;j++){
      int s = bk[j];
      acc = fmaf(dinv[s], F[(size_t)s*CC + f], acc);
    }
    atomicAdd(&AGG[(size_t)d*CC + f], dd*acc);
  }
}

// ---------------- K3: mid
//  [0,256):   G = relu(AGG1 + b1) @ [Wmu|Wls]   (8 rows/block)
//  [256,512): seed out with biases: out_mu = bmu, out_ls = bls (float4 stores)
__global__ __launch_bounds__(256) void k_mid(
  const float* __restrict__ AGG1, const float* __restrict__ b1,
  const float* __restrict__ Wmu, const float* __restrict__ Wls,
  const float* __restrict__ bmu, const float* __restrict__ bls,
  float* __restrict__ G, float* __restrict__ out)
{
  __shared__ float la[8][CC];
  int b = blockIdx.x, t = threadIdx.x;
  if (b < 256) {
    int row0 = b*8;
    #pragma unroll
    for (int i=0;i<4;i++){
      int idx = i*256 + t;
      float v = AGG1[(size_t)row0*CC + idx] + b1[idx & 127];
      la[idx>>7][idx&127] = v > 0.f ? v : 0.f;
    }
    __syncthreads();
    int f = t & 127, rh = t >> 7;
    int g = f & 63;
    const float* W = (f < 64) ? Wmu : Wls;
    float o[4] = {0.f,0.f,0.f,0.f};
    #pragma unroll 4
    for (int k=0;k<CC;k++){
      float w = W[k*64 + g];
      o[0] = fmaf(la[rh*4+0][k], w, o[0]);
      o[1] = fmaf(la[rh*4+1][k], w, o[1]);
      o[2] = fmaf(la[rh*4+2][k], w, o[2]);
      o[3] = fmaf(la[rh*4+3][k], w, o[3]);
    }
    #pragma unroll
    for (int i=0;i<4;i++)
      G[(size_t)(row0 + rh*4 + i)*CC + f] = o[i];
  } else {
    int i = (b-256)*256 + t;            // 0..65535 float4 over out (2048*128 floats)
    int g4 = (i & 15)*4;
    const float* bb = (i < 32768) ? bmu : bls;
    ((float4*)out)[i] = make_float4(bb[g4], bb[g4+1], bb[g4+2], bb[g4+3]);
  }
}

// ---------------- K4: out += Â G  (atomics straight into d_out, bias pre-seeded)
__global__ __launch_bounds__(256) void k_layer2(
  const float* __restrict__ SpRaw, const float* __restrict__ G, const float* __restrict__ dinv,
  const int* __restrict__ cnt, const u16* __restrict__ bucket, float* __restrict__ out)
{
  int b = blockIdx.x, t = threadIdx.x;
  int f = t & 127, g = f & 63;
  size_t obase = (f < 64) ? 0 : (size_t)NN*64;
  if (b < 256) {
    int half = t >> 7;
    int dbase = (b>>2)*16 + half*8;
    int r0 = (b&3)*256;
    float acc[8];
    #pragma unroll
    for (int j=0;j<8;j++) acc[j] = 0.f;
    #pragma unroll 4
    for (int r=r0; r<r0+256; ++r){
      float fv = G[(size_t)r*CC + f] * dinv[r];
      const float4* sp4 = (const float4*)(SpRaw + (size_t)r*HALF + dbase);
      float4 s0 = sp4[0], s1 = sp4[1];
      acc[0] = fmaf(s0.x, fv, acc[0]);
      acc[1] = fmaf(s0.y, fv, acc[1]);
      acc[2] = fmaf(s0.z, fv, acc[2]);
      acc[3] = fmaf(s0.w, fv, acc[3]);
      acc[4] = fmaf(s1.x, fv, acc[4]);
      acc[5] = fmaf(s1.y, fv, acc[5]);
      acc[6] = fmaf(s1.z, fv, acc[6]);
      acc[7] = fmaf(s1.w, fv, acc[7]);
    }
    #pragma unroll
    for (int j=0;j<8;j++)
      atomicAdd(&out[obase + (size_t)(dbase+j)*64 + g], acc[j]*dinv[dbase+j]);
  } else {
    int idx = b - 256;
    int d = idx*2 + (t>>7);
    float dd = dinv[d];
    float acc = dd * G[(size_t)d*CC + f];
    int m = cnt[d]; m = m > CAP ? CAP : m;
    const u16* bk = bucket + d*CAP;
    for (int j=0;j<m;j++){
      int s = bk[j];
      acc = fmaf(dinv[s], G[(size_t)s*CC + f], acc);
    }
    atomicAdd(&out[obase + (size_t)d*64 + g], dd*acc);
  }
}

extern "C" void kernel_launch(void* const* d_in, const int* in_sizes, int n_in,
                              void* d_out, int out_size, void* d_ws, size_t ws_size,
                              hipStream_t stream)
{
  (void)in_sizes; (void)n_in; (void)out_size; (void)ws_size;
  const float* x   = (const float*)d_in[0];
  const float* my  = (const float*)d_in[1];
  const float* W1  = (const float*)d_in[2];
  const float* b1  = (const float*)d_in[3];
  const float* Wmu = (const float*)d_in[4];
  const float* bmu = (const float*)d_in[5];
  const float* Wls = (const float*)d_in[6];
  const float* bls = (const float*)d_in[7];
  const int*   ei  = (const int*)d_in[8];
  float* out = (float*)d_out;
  char* ws = (char*)d_ws;

  // ws layout — memset covers [0, 1060928): cnt, colsum, done, AGG1
  int*   cnt    = (int*)  (ws + 0);        //    8192 B (memset 0)
  float* colsum = (float*)(ws + 8192);     //    4096 B (memset 0)
  int*   done   = (int*)  (ws + 12288);    //      64 B (memset 0)
  float* AGG1   = (float*)(ws + 12352);    // 1048576 B (memset 0)
  float* dinv   = (float*)(ws + 1060928);  //    8192 B
  u16*   bucket = (u16*)  (ws + 1069120);  //  524288 B
  float* SpRaw  = (float*)(ws + 1593408);  // 4194304 B
  float* H0     = (float*)(ws + 5787712);  // 1048576 B
  float* G      = (float*)(ws + 6836288);  // 1048576 B

  hipMemsetAsync(ws, 0, 1060928, stream);
  k_prep  <<<640,  256, 0, stream>>>(my, ei, x, W1, SpRaw, colsum, cnt, bucket, done, dinv, H0);
  k_layer1<<<1280, 256, 0, stream>>>(SpRaw, H0, dinv, cnt, bucket, AGG1);
  k_mid   <<<512,  256, 0, stream>>>(AGG1, b1, Wmu, Wls, bmu, bls, G, out);
  k_layer2<<<1280, 256, 0, stream>>>(SpRaw, G, dinv, cnt, bucket, out);
}

// Round 10
// 176.049 us; speedup vs baseline: 2.1650x; 1.0694x over previous
//
#include <hip/hip_runtime.h>

#define NN 2048
#define HALF 1024
#define CC 128
#define EE 65536
#define CAP 128

typedef unsigned short u16;

__device__ __forceinline__ float sigm(float v){ return 1.0f/(1.0f + __expf(-v)); }

// dinv for rows known < 1024 (dense block rows)
__device__ __forceinline__ float dinv_lo(int i, const int* __restrict__ cnt,
                                         const float* __restrict__ colsum){
  return rsqrtf(1.0f + (float)cnt[i] + colsum[i]);
}
// dinv for any row
__device__ __forceinline__ float dinv_any(int i, const int* __restrict__ cnt,
                                          const float* __restrict__ colsum){
  float cs = (i < HALF) ? colsum[i] : 0.0f;
  return rsqrtf(1.0f + (float)cnt[i] + cs);
}

// ---------------- K1: prep (640 blocks) — no done-counter, no tail
//  [0,128):   SpRaw[r][c]=sigm(my[r][c]) (coalesced) + colsum atomics
//  [128,384): bucket sparse edges by dst
//  [384,640): H0 = x @ W1  (8 rows/block, LDS-staged)
__global__ __launch_bounds__(256) void k_prep(
    const float* __restrict__ my, const int* __restrict__ ei, const float* __restrict__ x,
    const float* __restrict__ W1,
    float* __restrict__ SpRaw, float* __restrict__ colsum,
    int* __restrict__ cnt, u16* __restrict__ bucket, float* __restrict__ H0)
{
  __shared__ float la[8][CC];
  int b = blockIdx.x, t = threadIdx.x;
  if (b < 128) {
    int c0 = t*4;
    float cs0=0.f, cs1=0.f, cs2=0.f, cs3=0.f;
    #pragma unroll 2
    for (int rr=0; rr<8; ++rr){
      int r = b*8 + rr;
      float4 v = *(const float4*)(my + (size_t)r*NN + c0);
      float s0=sigm(v.x), s1=sigm(v.y), s2=sigm(v.z), s3=sigm(v.w);
      *(float4*)(SpRaw + (size_t)r*HALF + c0) = make_float4(s0,s1,s2,s3);
      cs0+=s0; cs1+=s1; cs2+=s2; cs3+=s3;
    }
    atomicAdd(&colsum[c0+0], cs0);
    atomicAdd(&colsum[c0+1], cs1);
    atomicAdd(&colsum[c0+2], cs2);
    atomicAdd(&colsum[c0+3], cs3);
  } else if (b < 384) {
    int e = (b-128)*256 + t;
    int s = ei[e], d = ei[EE + e];
    int slot = atomicAdd(&cnt[d], 1);
    if (slot < CAP) bucket[d*CAP + slot] = (u16)s;
  } else {
    int row0 = (b-384)*8;
    #pragma unroll
    for (int i=0;i<4;i++){
      int idx = i*256 + t;
      la[idx>>7][idx&127] = x[(size_t)row0*CC + idx];
    }
    __syncthreads();
    int f = t & 127, rh = t >> 7;
    float o[4] = {0.f,0.f,0.f,0.f};
    #pragma unroll 4
    for (int k=0;k<CC;k++){
      float w = W1[k*CC + f];
      o[0] = fmaf(la[rh*4+0][k], w, o[0]);
      o[1] = fmaf(la[rh*4+1][k], w, o[1]);
      o[2] = fmaf(la[rh*4+2][k], w, o[2]);
      o[3] = fmaf(la[rh*4+3][k], w, o[3]);
    }
    #pragma unroll
    for (int i=0;i<4;i++)
      H0[(size_t)(row0 + rh*4 + i)*CC + f] = o[i];
  }
}

// ---------------- K2: AGG1 = Â H0  (dense K-split + sparse; dinv computed inline)
__global__ __launch_bounds__(256) void k_layer1(
  const float* __restrict__ SpRaw, const float* __restrict__ F,
  const int* __restrict__ cnt, const float* __restrict__ colsum,
  const u16* __restrict__ bucket, float* __restrict__ AGG)
{
  int b = blockIdx.x, t = threadIdx.x;
  if (b < 256) {
    int f = t & 127, half = t >> 7;
    int dbase = (b>>2)*16 + half*8;
    int r0 = (b&3)*256;
    float acc[8];
    #pragma unroll
    for (int j=0;j<8;j++) acc[j] = 0.f;
    #pragma unroll 4
    for (int r=r0; r<r0+256; ++r){
      float fv = F[(size_t)r*CC + f] * dinv_lo(r, cnt, colsum);
      const float4* sp4 = (const float4*)(SpRaw + (size_t)r*HALF + dbase);
      float4 s0 = sp4[0], s1 = sp4[1];
      acc[0] = fmaf(s0.x, fv, acc[0]);
      acc[1] = fmaf(s0.y, fv, acc[1]);
      acc[2] = fmaf(s0.z, fv, acc[2]);
      acc[3] = fmaf(s0.w, fv, acc[3]);
      acc[4] = fmaf(s1.x, fv, acc[4]);
      acc[5] = fmaf(s1.y, fv, acc[5]);
      acc[6] = fmaf(s1.z, fv, acc[6]);
      acc[7] = fmaf(s1.w, fv, acc[7]);
    }
    #pragma unroll
    for (int j=0;j<8;j++)
      atomicAdd(&AGG[(size_t)(dbase+j)*CC + f], acc[j]*dinv_lo(dbase+j, cnt, colsum));
  } else {
    int idx = b - 256;
    int d = idx*2 + (t>>7), f = t & 127;
    float dd = dinv_any(d, cnt, colsum);
    float acc = dd * F[(size_t)d*CC + f];
    int m = cnt[d]; m = m > CAP ? CAP : m;
    const u16* bk = bucket + d*CAP;
    for (int j=0;j<m;j++){
      int s = bk[j];
      acc = fmaf(dinv_any(s, cnt, colsum), F[(size_t)s*CC + f], acc);
    }
    atomicAdd(&AGG[(size_t)d*CC + f], dd*acc);
  }
}

// ---------------- K3: mid
//  [0,256):   G = relu(AGG1 + b1) @ [Wmu|Wls]   (8 rows/block)
//  [256,512): seed out with biases
__global__ __launch_bounds__(256) void k_mid(
  const float* __restrict__ AGG1, const float* __restrict__ b1,
  const float* __restrict__ Wmu, const float* __restrict__ Wls,
  const float* __restrict__ bmu, const float* __restrict__ bls,
  float* __restrict__ G, float* __restrict__ out)
{
  __shared__ float la[8][CC];
  int b = blockIdx.x, t = threadIdx.x;
  if (b < 256) {
    int row0 = b*8;
    #pragma unroll
    for (int i=0;i<4;i++){
      int idx = i*256 + t;
      float v = AGG1[(size_t)row0*CC + idx] + b1[idx & 127];
      la[idx>>7][idx&127] = v > 0.f ? v : 0.f;
    }
    __syncthreads();
    int f = t & 127, rh = t >> 7;
    int g = f & 63;
    const float* W = (f < 64) ? Wmu : Wls;
    float o[4] = {0.f,0.f,0.f,0.f};
    #pragma unroll 4
    for (int k=0;k<CC;k++){
      float w = W[k*64 + g];
      o[0] = fmaf(la[rh*4+0][k], w, o[0]);
      o[1] = fmaf(la[rh*4+1][k], w, o[1]);
      o[2] = fmaf(la[rh*4+2][k], w, o[2]);
      o[3] = fmaf(la[rh*4+3][k], w, o[3]);
    }
    #pragma unroll
    for (int i=0;i<4;i++)
      G[(size_t)(row0 + rh*4 + i)*CC + f] = o[i];
  } else {
    int i = (b-256)*256 + t;            // 0..65535 float4 over out (2048*128 floats)
    int g4 = (i & 15)*4;
    const float* bb = (i < 32768) ? bmu : bls;
    ((float4*)out)[i] = make_float4(bb[g4], bb[g4+1], bb[g4+2], bb[g4+3]);
  }
}

// ---------------- K4: out += Â G  (atomics straight into d_out, bias pre-seeded)
__global__ __launch_bounds__(256) void k_layer2(
  const float* __restrict__ SpRaw, const float* __restrict__ G,
  const int* __restrict__ cnt, const float* __restrict__ colsum,
  const u16* __restrict__ bucket, float* __restrict__ out)
{
  int b = blockIdx.x, t = threadIdx.x;
  int f = t & 127, g = f & 63;
  size_t obase = (f < 64) ? 0 : (size_t)NN*64;
  if (b < 256) {
    int half = t >> 7;
    int dbase = (b>>2)*16 + half*8;
    int r0 = (b&3)*256;
    float acc[8];
    #pragma unroll
    for (int j=0;j<8;j++) acc[j] = 0.f;
    #pragma unroll 4
    for (int r=r0; r<r0+256; ++r){
      float fv = G[(size_t)r*CC + f] * dinv_lo(r, cnt, colsum);
      const float4* sp4 = (const float4*)(SpRaw + (size_t)r*HALF + dbase);
      float4 s0 = sp4[0], s1 = sp4[1];
      acc[0] = fmaf(s0.x, fv, acc[0]);
      acc[1] = fmaf(s0.y, fv, acc[1]);
      acc[2] = fmaf(s0.z, fv, acc[2]);
      acc[3] = fmaf(s0.w, fv, acc[3]);
      acc[4] = fmaf(s1.x, fv, acc[4]);
      acc[5] = fmaf(s1.y, fv, acc[5]);
      acc[6] = fmaf(s1.z, fv, acc[6]);
      acc[7] = fmaf(s1.w, fv, acc[7]);
    }
    #pragma unroll
    for (int j=0;j<8;j++)
      atomicAdd(&out[obase + (size_t)(dbase+j)*64 + g],
                acc[j]*dinv_lo(dbase+j, cnt, colsum));
  } else {
    int idx = b - 256;
    int d = idx*2 + (t>>7);
    float dd = dinv_any(d, cnt, colsum);
    float acc = dd * G[(size_t)d*CC + f];
    int m = cnt[d]; m = m > CAP ? CAP : m;
    const u16* bk = bucket + d*CAP;
    for (int j=0;j<m;j++){
      int s = bk[j];
      acc = fmaf(dinv_any(s, cnt, colsum), G[(size_t)s*CC + f], acc);
    }
    atomicAdd(&out[obase + (size_t)d*64 + g], dd*acc);
  }
}

extern "C" void kernel_launch(void* const* d_in, const int* in_sizes, int n_in,
                              void* d_out, int out_size, void* d_ws, size_t ws_size,
                              hipStream_t stream)
{
  (void)in_sizes; (void)n_in; (void)out_size; (void)ws_size;
  const float* x   = (const float*)d_in[0];
  const float* my  = (const float*)d_in[1];
  const float* W1  = (const float*)d_in[2];
  const float* b1  = (const float*)d_in[3];
  const float* Wmu = (const float*)d_in[4];
  const float* bmu = (const float*)d_in[5];
  const float* Wls = (const float*)d_in[6];
  const float* bls = (const float*)d_in[7];
  const int*   ei  = (const int*)d_in[8];
  float* out = (float*)d_out;
  char* ws = (char*)d_ws;

  // ws layout — memset covers [0, 1060864): cnt, colsum, AGG1
  int*   cnt    = (int*)  (ws + 0);        //    8192 B (memset 0)
  float* colsum = (float*)(ws + 8192);     //    4096 B (memset 0)
  float* AGG1   = (float*)(ws + 12288);    // 1048576 B (memset 0)
  u16*   bucket = (u16*)  (ws + 1060864);  //  524288 B
  float* SpRaw  = (float*)(ws + 1585152);  // 4194304 B
  float* H0     = (float*)(ws + 5779456);  // 1048576 B
  float* G      = (float*)(ws + 6828032);  // 1048576 B

  hipMemsetAsync(ws, 0, 1060864, stream);
  k_prep  <<<640,  256, 0, stream>>>(my, ei, x, W1, SpRaw, colsum, cnt, bucket, H0);
  k_layer1<<<1280, 256, 0, stream>>>(SpRaw, H0, cnt, colsum, bucket, AGG1);
  k_mid   <<<512,  256, 0, stream>>>(AGG1, b1, Wmu, Wls, bmu, bls, G, out);
  k_layer2<<<1280, 256, 0, stream>>>(SpRaw, G, cnt, colsum, bucket, out);
}

// Round 11
// 173.830 us; speedup vs baseline: 2.1927x; 1.0128x over previous
//
#include <hip/hip_runtime.h>

#define NN 2048
#define HALF 1024
#define CC 128
#define EE 65536
#define CAP 128

typedef unsigned short u16;

__device__ __forceinline__ float sigm(float v){ return 1.0f/(1.0f + __expf(-v)); }

__device__ __forceinline__ float dinv_lo(int i, const int* __restrict__ cnt,
                                         const float* __restrict__ colsum){
  return rsqrtf(1.0f + (float)cnt[i] + colsum[i]);
}
__device__ __forceinline__ float dinv_any(int i, const int* __restrict__ cnt,
                                          const float* __restrict__ colsum){
  float cs = (i < HALF) ? colsum[i] : 0.0f;
  return rsqrtf(1.0f + (float)cnt[i] + cs);
}

// ---------------- K1: prep (640 blocks)
//  all blocks: strided zero of AGG1 + bias-seed of out (plain float4 stores)
//  [0,128):   SpRaw[r][c]=sigm(my[r][c]) (coalesced) + colsum atomics
//  [128,384): bucket sparse edges by dst
//  [384,640): H0 = x @ W1  (8 rows/block, LDS-staged)
__global__ __launch_bounds__(256) void k_prep(
    const float* __restrict__ my, const int* __restrict__ ei, const float* __restrict__ x,
    const float* __restrict__ W1,
    const float* __restrict__ bmu, const float* __restrict__ bls,
    float* __restrict__ SpRaw, float* __restrict__ colsum,
    int* __restrict__ cnt, u16* __restrict__ bucket, float* __restrict__ H0,
    float* __restrict__ AGG1, float* __restrict__ out)
{
  __shared__ float la[8][CC];
  int b = blockIdx.x, t = threadIdx.x;
  int gid = b*256 + t;                    // 0..163839
  if (gid < 65536) {
    ((float4*)AGG1)[gid] = make_float4(0.f,0.f,0.f,0.f);
  } else if (gid < 131072) {
    int i = gid - 65536;                  // float4 index into out (65536 total)
    int g4 = (i & 15)*4;
    const float* bb = (i < 32768) ? bmu : bls;
    ((float4*)out)[i] = make_float4(bb[g4], bb[g4+1], bb[g4+2], bb[g4+3]);
  }

  if (b < 128) {
    int c0 = t*4;
    float cs0=0.f, cs1=0.f, cs2=0.f, cs3=0.f;
    #pragma unroll 2
    for (int rr=0; rr<8; ++rr){
      int r = b*8 + rr;
      float4 v = *(const float4*)(my + (size_t)r*NN + c0);
      float s0=sigm(v.x), s1=sigm(v.y), s2=sigm(v.z), s3=sigm(v.w);
      *(float4*)(SpRaw + (size_t)r*HALF + c0) = make_float4(s0,s1,s2,s3);
      cs0+=s0; cs1+=s1; cs2+=s2; cs3+=s3;
    }
    atomicAdd(&colsum[c0+0], cs0);
    atomicAdd(&colsum[c0+1], cs1);
    atomicAdd(&colsum[c0+2], cs2);
    atomicAdd(&colsum[c0+3], cs3);
  } else if (b < 384) {
    int e = (b-128)*256 + t;
    int s = ei[e], d = ei[EE + e];
    int slot = atomicAdd(&cnt[d], 1);
    if (slot < CAP) bucket[d*CAP + slot] = (u16)s;
  } else {
    int row0 = (b-384)*8;
    #pragma unroll
    for (int i=0;i<4;i++){
      int idx = i*256 + t;
      la[idx>>7][idx&127] = x[(size_t)row0*CC + idx];
    }
    __syncthreads();
    int f = t & 127, rh = t >> 7;
    float o[4] = {0.f,0.f,0.f,0.f};
    #pragma unroll 4
    for (int k=0;k<CC;k++){
      float w = W1[k*CC + f];
      o[0] = fmaf(la[rh*4+0][k], w, o[0]);
      o[1] = fmaf(la[rh*4+1][k], w, o[1]);
      o[2] = fmaf(la[rh*4+2][k], w, o[2]);
      o[3] = fmaf(la[rh*4+3][k], w, o[3]);
    }
    #pragma unroll
    for (int i=0;i<4;i++)
      H0[(size_t)(row0 + rh*4 + i)*CC + f] = o[i];
  }
}

// ---------------- K2: AGG1 = Â H0  (dense K-split w/ LDS-staged dinv + sparse)
__global__ __launch_bounds__(256) void k_layer1(
  const float* __restrict__ SpRaw, const float* __restrict__ F,
  const int* __restrict__ cnt, const float* __restrict__ colsum,
  const u16* __restrict__ bucket, float* __restrict__ AGG)
{
  __shared__ float ld[256];
  int b = blockIdx.x, t = threadIdx.x;
  if (b < 256) {
    int f = t & 127, half = t >> 7;
    int dbase = (b>>2)*16 + half*8;
    int r0 = (b&3)*256;
    ld[t] = dinv_lo(r0 + t, cnt, colsum);
    __syncthreads();
    float acc[8];
    #pragma unroll
    for (int j=0;j<8;j++) acc[j] = 0.f;
    #pragma unroll 4
    for (int rr=0; rr<256; ++rr){
      int r = r0 + rr;
      float fv = F[(size_t)r*CC + f] * ld[rr];
      const float4* sp4 = (const float4*)(SpRaw + (size_t)r*HALF + dbase);
      float4 s0 = sp4[0], s1 = sp4[1];
      acc[0] = fmaf(s0.x, fv, acc[0]);
      acc[1] = fmaf(s0.y, fv, acc[1]);
      acc[2] = fmaf(s0.z, fv, acc[2]);
      acc[3] = fmaf(s0.w, fv, acc[3]);
      acc[4] = fmaf(s1.x, fv, acc[4]);
      acc[5] = fmaf(s1.y, fv, acc[5]);
      acc[6] = fmaf(s1.z, fv, acc[6]);
      acc[7] = fmaf(s1.w, fv, acc[7]);
    }
    #pragma unroll
    for (int j=0;j<8;j++)
      atomicAdd(&AGG[(size_t)(dbase+j)*CC + f], acc[j]*dinv_lo(dbase+j, cnt, colsum));
  } else {
    int idx = b - 256;
    int d = idx*2 + (t>>7), f = t & 127;
    float dd = dinv_any(d, cnt, colsum);
    float acc = dd * F[(size_t)d*CC + f];
    int m = cnt[d]; m = m > CAP ? CAP : m;
    const u16* bk = bucket + d*CAP;
    for (int j=0;j<m;j++){
      int s = bk[j];
      acc = fmaf(dinv_any(s, cnt, colsum), F[(size_t)s*CC + f], acc);
    }
    atomicAdd(&AGG[(size_t)d*CC + f], dd*acc);
  }
}

// ---------------- K3: mid (256 blocks): G' = ( relu(AGG1 + b1) @ [Wmu|Wls] ) * dinv[row]
__global__ __launch_bounds__(256) void k_mid(
  const float* __restrict__ AGG1, const float* __restrict__ b1,
  const float* __restrict__ Wmu, const float* __restrict__ Wls,
  const int* __restrict__ cnt, const float* __restrict__ colsum,
  float* __restrict__ G)
{
  __shared__ float la[8][CC];
  int b = blockIdx.x, t = threadIdx.x;
  int row0 = b*8;
  #pragma unroll
  for (int i=0;i<4;i++){
    int idx = i*256 + t;
    float v = AGG1[(size_t)row0*CC + idx] + b1[idx & 127];
    la[idx>>7][idx&127] = v > 0.f ? v : 0.f;
  }
  __syncthreads();
  int f = t & 127, rh = t >> 7;
  int g = f & 63;
  const float* W = (f < 64) ? Wmu : Wls;
  float o[4] = {0.f,0.f,0.f,0.f};
  #pragma unroll 4
  for (int k=0;k<CC;k++){
    float w = W[k*64 + g];
    o[0] = fmaf(la[rh*4+0][k], w, o[0]);
    o[1] = fmaf(la[rh*4+1][k], w, o[1]);
    o[2] = fmaf(la[rh*4+2][k], w, o[2]);
    o[3] = fmaf(la[rh*4+3][k], w, o[3]);
  }
  #pragma unroll
  for (int i=0;i<4;i++){
    int row = row0 + rh*4 + i;
    G[(size_t)row*CC + f] = o[i] * dinv_any(row, cnt, colsum);
  }
}

// ---------------- K4: out += Â-apply on pre-scaled G'  (atomics into bias-seeded d_out)
__global__ __launch_bounds__(256) void k_layer2(
  const float* __restrict__ SpRaw, const float* __restrict__ G,
  const int* __restrict__ cnt, const float* __restrict__ colsum,
  const u16* __restrict__ bucket, float* __restrict__ out)
{
  int b = blockIdx.x, t = threadIdx.x;
  int f = t & 127, g = f & 63;
  size_t obase = (f < 64) ? 0 : (size_t)NN*64;
  if (b < 256) {
    int half = t >> 7;
    int dbase = (b>>2)*16 + half*8;
    int r0 = (b&3)*256;
    float acc[8];
    #pragma unroll
    for (int j=0;j<8;j++) acc[j] = 0.f;
    #pragma unroll 4
    for (int r=r0; r<r0+256; ++r){
      float fv = G[(size_t)r*CC + f];
      const float4* sp4 = (const float4*)(SpRaw + (size_t)r*HALF + dbase);
      float4 s0 = sp4[0], s1 = sp4[1];
      acc[0] = fmaf(s0.x, fv, acc[0]);
      acc[1] = fmaf(s0.y, fv, acc[1]);
      acc[2] = fmaf(s0.z, fv, acc[2]);
      acc[3] = fmaf(s0.w, fv, acc[3]);
      acc[4] = fmaf(s1.x, fv, acc[4]);
      acc[5] = fmaf(s1.y, fv, acc[5]);
      acc[6] = fmaf(s1.z, fv, acc[6]);
      acc[7] = fmaf(s1.w, fv, acc[7]);
    }
    #pragma unroll
    for (int j=0;j<8;j++)
      atomicAdd(&out[obase + (size_t)(dbase+j)*64 + g],
                acc[j]*dinv_lo(dbase+j, cnt, colsum));
  } else {
    int idx = b - 256;
    int d = idx*2 + (t>>7);
    float acc = G[(size_t)d*CC + f];            // self term: dinv[d]*G[d] == G'[d]
    int m = cnt[d]; m = m > CAP ? CAP : m;
    const u16* bk = bucket + d*CAP;
    for (int j=0;j<m;j++){
      int s = bk[j];
      acc += G[(size_t)s*CC + f];               // dinv[s]*G[s] == G'[s]
    }
    atomicAdd(&out[obase + (size_t)d*64 + g], acc * dinv_any(d, cnt, colsum));
  }
}

extern "C" void kernel_launch(void* const* d_in, const int* in_sizes, int n_in,
                              void* d_out, int out_size, void* d_ws, size_t ws_size,
                              hipStream_t stream)
{
  (void)in_sizes; (void)n_in; (void)out_size; (void)ws_size;
  const float* x   = (const float*)d_in[0];
  const float* my  = (const float*)d_in[1];
  const float* W1  = (const float*)d_in[2];
  const float* b1  = (const float*)d_in[3];
  const float* Wmu = (const float*)d_in[4];
  const float* bmu = (const float*)d_in[5];
  const float* Wls = (const float*)d_in[6];
  const float* bls = (const float*)d_in[7];
  const int*   ei  = (const int*)d_in[8];
  float* out = (float*)d_out;
  char* ws = (char*)d_ws;

  // ws layout — memset covers only [0, 12288): cnt, colsum
  int*   cnt    = (int*)  (ws + 0);        //    8192 B (memset 0)
  float* colsum = (float*)(ws + 8192);     //    4096 B (memset 0)
  float* AGG1   = (float*)(ws + 12288);    // 1048576 B (zeroed in k_prep)
  u16*   bucket = (u16*)  (ws + 1060864);  //  524288 B
  float* SpRaw  = (float*)(ws + 1585152);  // 4194304 B
  float* H0     = (float*)(ws + 5779456);  // 1048576 B
  float* G      = (float*)(ws + 6828032);  // 1048576 B

  hipMemsetAsync(ws, 0, 12288, stream);
  k_prep  <<<640,  256, 0, stream>>>(my, ei, x, W1, bmu, bls,
                                     SpRaw, colsum, cnt, bucket, H0, AGG1, out);
  k_layer1<<<1280, 256, 0, stream>>>(SpRaw, H0, cnt, colsum, bucket, AGG1);
  k_mid   <<<256,  256, 0, stream>>>(AGG1, b1, Wmu, Wls, cnt, colsum, G);
  k_layer2<<<1280, 256, 0, stream>>>(SpRaw, G, cnt, colsum, bucket, out);
}